// Round 12
// baseline (237.982 us; speedup 1.0000x reference)
//
#include <hip/hip_runtime.h>
#include <hip/hip_bf16.h>

// All tensors are float32 (verified R2/R3: runtime dtype probe took the f32
// branch; bf16 interpretation NaN'd in R1/R4). Output float32.

#define NB 16
#define NL 256
#define NLQ 64
#define NDIN 32
#define NET 128
#define NH 4
#define NETK 32

// ---------------------------------------------------------------------------
// Kernel 1: time embedding + K/Q projection, 8 rows per block.
// grid = 512 (k-rows) + 8 (q-rows) = 520 blocks, 128 threads.
// ---------------------------------------------------------------------------
__global__ __launch_bounds__(128) void k_embed_proj(
    const float* __restrict__ ts, const float* __restrict__ query,
    const float* __restrict__ w_lin, const float* __restrict__ b_lin,
    const float* __restrict__ w_per, const float* __restrict__ b_per,
    const float* __restrict__ Wk, const float* __restrict__ bk,
    const float* __restrict__ Wq, const float* __restrict__ bq,
    float* __restrict__ kproj, float* __restrict__ qproj) {
  __shared__ float emb[8 * NET];
  int g = blockIdx.x;
  int j = threadIdx.x;
  bool isQ = (g >= 512);
  int base = (isQ ? g - 512 : g) * 8;
  float wl_ = w_lin[0], bl_ = b_lin[0];
  float wp = (j > 0) ? w_per[j - 1] : 0.f;
  float bp = (j > 0) ? b_per[j - 1] : 0.f;
#pragma unroll
  for (int rr = 0; rr < 8; rr++) {
    float t = isQ ? query[base + rr] : ts[base + rr];
    emb[rr * NET + j] = (j == 0) ? (t * wl_ + bl_) : sinf(t * wp + bp);
  }
  __syncthreads();
  const float* W = isQ ? Wq : Wk;
  float bias = isQ ? bq[j] : bk[j];
  float acc[8];
#pragma unroll
  for (int rr = 0; rr < 8; rr++) acc[rr] = bias;
#pragma unroll 4
  for (int i = 0; i < NET; i++) {
    float wv = W[i * NET + j];
#pragma unroll
    for (int rr = 0; rr < 8; rr++) acc[rr] += emb[rr * NET + i] * wv;
  }
  float* dst = isQ ? qproj : kproj;
#pragma unroll
  for (int rr = 0; rr < 8; rr++) dst[(size_t)(base + rr) * NET + j] = acc[rr];
}

// ---------------------------------------------------------------------------
// Kernel 2: attention. block = (b, h, qgroup of 4). grid = 16*4*16 = 1024
// blocks, 256 threads. LDS ~38 KB.
// Masked softmax collapses per-channel: att_x = sum(e*m*x)/sum(e*m);
// all-masked channel => uniform softmax => mean(x), att_m = 0.
// ---------------------------------------------------------------------------
__global__ __launch_bounds__(256) void k_attn(
    const float* __restrict__ x, const float* __restrict__ mask,
    const float* __restrict__ qproj, const float* __restrict__ kproj,
    float* __restrict__ att) {
  const float SC = 0.17677669529663687f;  // 1/sqrt(32)
  int blk = blockIdx.x;
  int qg = blk & 15;
  int h  = (blk >> 4) & 3;
  int b  = blk >> 6;
  int t  = threadIdx.x;

  __shared__ float xs[NL * NDIN];  // 32 KB
  __shared__ unsigned mb[NL];      // 1 KB
  __shared__ float es[4 * NL];     // 4 KB
  __shared__ float qs[4 * NETK];   // 512 B

  if (t < 128) {
    int qq = t >> 5, i = t & 31;
    qs[t] = qproj[(qg * 4 + qq) * NET + h * NETK + i];
  }
  {
    const float4* src = (const float4*)(x + (size_t)b * NL * NDIN);
    float4* dst = (float4*)xs;
#pragma unroll
    for (int u = 0; u < 8; u++) dst[t + 256 * u] = src[t + 256 * u];
  }
  {
    const float4* mr4 = (const float4*)(mask + (size_t)(b * NL + t) * NDIN);
    unsigned bits = 0;
#pragma unroll
    for (int u = 0; u < 8; u++) {
      float4 m = mr4[u];
      bits |= (m.x != 0.f ? 1u : 0u) << (4 * u);
      bits |= (m.y != 0.f ? 1u : 0u) << (4 * u + 1);
      bits |= (m.z != 0.f ? 1u : 0u) << (4 * u + 2);
      bits |= (m.w != 0.f ? 1u : 0u) << (4 * u + 3);
    }
    mb[t] = bits;
  }
  __syncthreads();

  // phase A: scores -> exp
  {
    float kr[NETK];
    const float4* kp =
        (const float4*)(kproj + (size_t)(b * NL + t) * NET + h * NETK);
#pragma unroll
    for (int i = 0; i < 8; i++) {
      float4 v = kp[i];
      kr[4 * i] = v.x; kr[4 * i + 1] = v.y;
      kr[4 * i + 2] = v.z; kr[4 * i + 3] = v.w;
    }
#pragma unroll
    for (int qq = 0; qq < 4; qq++) {
      const float* qv = &qs[qq * NETK];
      float s0 = 0.f, s1 = 0.f;
#pragma unroll
      for (int i = 0; i < NETK; i += 2) {
        s0 += qv[i] * kr[i];
        s1 += qv[i + 1] * kr[i + 1];
      }
      es[qq * NL + t] = __expf((s0 + s1) * SC);
    }
  }
  __syncthreads();

  // phase B: lane pair (s = t&1) -> (qq = wave index, c)
  {
    int s = t & 1;
    int p = t >> 1;       // 0..127
    int qq = p >> 5;      // == wave id: uniform per wave
    int c  = p & 31;
    int k0 = s * 128;
    float den = 0.f, num = 0.f, sumx = 0.f;
#pragma unroll 4
    for (int k = k0; k < k0 + 128; k++) {
      float e  = es[qq * NL + k];
      float mv = ((mb[k] >> c) & 1u) ? 1.f : 0.f;
      float xv = xs[k * NDIN + c];
      sumx += xv;
      e *= mv;
      den += e;
      num += e * xv;
    }
    den  += __shfl_xor(den, 1, 64);
    num  += __shfl_xor(num, 1, 64);
    sumx += __shfl_xor(sumx, 1, 64);
    if (s == 0) {
      bool any = (den > 0.f);
      float ax = any ? (num / den) : (sumx * (1.f / 256.f));
      float am = any ? 1.f : 0.f;
      int q = qg * 4 + qq;
      float* ao = att + (size_t)((b * NLQ + q) * NH + h) * 64;
      ao[c]      = ax;
      ao[32 + c] = am;
    }
  }
}

// ---------------------------------------------------------------------------
// Kernel 3: out = att @ Wo + bo; XW = out @ W_ih + b_ih + b_hh.
// grid = B*LQ = 1024 blocks, 128 threads.
// ---------------------------------------------------------------------------
__global__ __launch_bounds__(128) void k_out_xw(
    const float* __restrict__ att,
    const float* __restrict__ Wo, const float* __restrict__ bo,
    const float* __restrict__ Wih, const float* __restrict__ bih,
    const float* __restrict__ bhh, float* __restrict__ XW) {
  int r = blockIdx.x;
  int j = threadIdx.x;
  __shared__ float arow[NH * 64];
  __shared__ float orow[NET];
  arow[j]       = att[(size_t)r * 256 + j];
  arow[j + 128] = att[(size_t)r * 256 + 128 + j];
  __syncthreads();
  float a0 = bo[j], a1 = 0.f, a2 = 0.f, a3 = 0.f;
#pragma unroll 8
  for (int u = 0; u < 256; u += 4) {
    a0 += arow[u]     * Wo[(u)     * NET + j];
    a1 += arow[u + 1] * Wo[(u + 1) * NET + j];
    a2 += arow[u + 2] * Wo[(u + 2) * NET + j];
    a3 += arow[u + 3] * Wo[(u + 3) * NET + j];
  }
  orow[j] = (a0 + a1) + (a2 + a3);
  __syncthreads();
  float b0 = bih[j] + bhh[j], b1 = 0.f, b2 = 0.f, b3 = 0.f;
#pragma unroll 8
  for (int e = 0; e < NET; e += 4) {
    b0 += orow[e]     * Wih[(e)     * NET + j];
    b1 += orow[e + 1] * Wih[(e + 1) * NET + j];
    b2 += orow[e + 2] * Wih[(e + 2) * NET + j];
    b3 += orow[e + 3] * Wih[(e + 3) * NET + j];
  }
  XW[(size_t)r * NET + j] = (b0 + b1) + (b2 + b3);
}

// ---------------------------------------------------------------------------
// broadcast of lane i's copy of v (readlane: pure VALU/SALU, no LDS pipe)
// ---------------------------------------------------------------------------
__device__ __forceinline__ float bcast(float v, int i) {
  return __int_as_float(__builtin_amdgcn_readlane(__float_as_int(v), i));
}

// regressor layer in lane-distributed form: lane l holds src[l], src[64+l];
// produces dst[l], dst[64+l]. Weights streamed coalesced from global.
__device__ __forceinline__ void layer_rl(float& slo, float& shi,
                                         const float* __restrict__ W,
                                         const float* __restrict__ bvec,
                                         int l) {
  float a = bvec[l], c = bvec[64 + l];
  float slo_in = slo, shi_in = shi;
#pragma unroll
  for (int i = 0; i < 64; i++) {
    float s = bcast(slo_in, i);
    a += s * W[i * NET + l];
    c += s * W[i * NET + 64 + l];
  }
#pragma unroll
  for (int i = 0; i < 64; i++) {
    float s = bcast(shi_in, i);
    a += s * W[(64 + i) * NET + l];
    c += s * W[(64 + i) * NET + 64 + l];
  }
  slo = a; shi = c;
}

// ---------------------------------------------------------------------------
// Kernel 4: sequential RNN (64 steps) + regressor. grid = 16, 64 threads
// (ONE wave). Lane l owns outputs (l, l+64); h lives in REGISTERS
// (2 floats/lane); cross-lane broadcast via v_readlane (constant lane index
// after unroll) — the 64-step loop contains NO __syncthreads and NO LDS
// h-traffic. Tests the barrier/LDS-turnaround-floor hypothesis directly
// (R6-R11: six barrier+LDS variants all 42-47 us).
// Weights as FOUR 64-float arrays (per-array <=64 = promotion granule:
// R10 2x64 promoted, R7 1x128 refused). XW staged to LDS (in-wave, no
// barrier needed; read per step, latency hidden under the FMA block).
// ---------------------------------------------------------------------------
__global__ __launch_bounds__(64, 1) void k_rnn(
    const float* __restrict__ XW, const float* __restrict__ Whh,
    const float* __restrict__ r1w, const float* __restrict__ r1b,
    const float* __restrict__ r2w, const float* __restrict__ r2b,
    const float* __restrict__ r3w, const float* __restrict__ r3b,
    const float* __restrict__ r4w, const float* __restrict__ r4b,
    float* __restrict__ out) {
  int b = blockIdx.x;
  int l = threadIdx.x;  // 0..63
  __shared__ float xwl[NLQ * NET];  // 32 KB

  // stage XW slice (coalesced float4; single wave -> no barrier needed)
  {
    const float4* src = (const float4*)(XW + (size_t)b * NLQ * NET);
    float4* dst = (float4*)xwl;
#pragma unroll
    for (int u = 0; u < 32; u++) dst[l + 64 * u] = src[l + 64 * u];
  }

  // W_hh columns l and l+64, each split into two 64-float arrays
  float w00[64], w01[64], w10[64], w11[64];
#pragma unroll
  for (int i = 0; i < 64; i++) w00[i] = Whh[i * NET + l];
#pragma unroll
  for (int i = 0; i < 64; i++) w01[i] = Whh[(64 + i) * NET + l];
#pragma unroll
  for (int i = 0; i < 64; i++) w10[i] = Whh[i * NET + l + 64];
#pragma unroll
  for (int i = 0; i < 64; i++) w11[i] = Whh[(64 + i) * NET + l + 64];

  float hlo = 0.f, hhi = 0.f;
  __syncthreads();  // 1 wave: compiles to waitcnt; orders xwl staging

  for (int t = 0; t < NLQ; t++) {
    float xw0 = xwl[t * NET + l];        // issued early, hides under FMAs
    float xw1 = xwl[t * NET + 64 + l];
    float hl = hlo, hh = hhi;
    float a0 = 0.f, a1 = 0.f, c0 = 0.f, c1 = 0.f;
#pragma unroll
    for (int i = 0; i < 64; i++) {
      float s = bcast(hl, i);
      a0 += s * w00[i];
      c0 += s * w10[i];
    }
#pragma unroll
    for (int i = 0; i < 64; i++) {
      float s = bcast(hh, i);
      a1 += s * w01[i];
      c1 += s * w11[i];
    }
    float z0 = (a0 + a1) + xw0;
    float z1 = (c0 + c1) + xw1;
    float e0 = __expf(2.f * z0);
    float e1 = __expf(2.f * z1);
    hlo = 1.f - 2.f / (e0 + 1.f);  // tanh(z0)
    hhi = 1.f - 2.f / (e1 + 1.f);  // tanh(z1)
  }

  // regressor: 3 x (128->128), lane-distributed, then 128->8
  layer_rl(hlo, hhi, r1w, r1b, l);
  layer_rl(hlo, hhi, r2w, r2b, l);
  layer_rl(hlo, hhi, r3w, r3b, l);
  {
    int jj = l & 7;
    float y = 0.f;
    float slo_in = hlo, shi_in = hhi;
#pragma unroll
    for (int i = 0; i < 64; i++) y += bcast(slo_in, i) * r4w[i * 8 + jj];
#pragma unroll
    for (int i = 0; i < 64; i++) y += bcast(shi_in, i) * r4w[(64 + i) * 8 + jj];
    if (l < 8) out[b * 8 + l] = y + r4b[l];
  }
}

// ---------------------------------------------------------------------------
extern "C" void kernel_launch(void* const* d_in, const int* in_sizes, int n_in,
                              void* d_out, int out_size, void* d_ws, size_t ws_size,
                              hipStream_t stream) {
  const float* x     = (const float*)d_in[0];
  const float* ts    = (const float*)d_in[1];
  const float* mask  = (const float*)d_in[2];
  const float* query = (const float*)d_in[3];
  const float* w_lin = (const float*)d_in[4];
  const float* b_lin = (const float*)d_in[5];
  const float* w_per = (const float*)d_in[6];
  const float* b_per = (const float*)d_in[7];
  const float* Wq    = (const float*)d_in[8];
  const float* bq    = (const float*)d_in[9];
  const float* Wk    = (const float*)d_in[10];
  const float* bk    = (const float*)d_in[11];
  const float* Wo    = (const float*)d_in[12];
  const float* bo    = (const float*)d_in[13];
  const float* Wih   = (const float*)d_in[14];
  const float* bih   = (const float*)d_in[15];
  const float* Whh   = (const float*)d_in[16];
  const float* bhh   = (const float*)d_in[17];
  const float* r1w   = (const float*)d_in[18];
  const float* r1b   = (const float*)d_in[19];
  const float* r2w   = (const float*)d_in[20];
  const float* r2b   = (const float*)d_in[21];
  const float* r3w   = (const float*)d_in[22];
  const float* r3b   = (const float*)d_in[23];
  const float* r4w   = (const float*)d_in[24];
  const float* r4b   = (const float*)d_in[25];
  float* out = (float*)d_out;

  float* ws    = (float*)d_ws;
  float* kproj = ws;                  // 4096*128 = 524288
  float* qproj = ws + 524288;         // 64*128   = 8192
  float* att   = ws + 532480;         // 1024*256 = 262144
  float* XW    = ws + 794624;         // 1024*128 = 131072

  k_embed_proj<<<520, 128, 0, stream>>>(
      ts, query, w_lin, b_lin, w_per, b_per, Wk, bk, Wq, bq, kproj, qproj);
  k_attn<<<NB * NH * 16, 256, 0, stream>>>(x, mask, qproj, kproj, att);
  k_out_xw<<<NB * NLQ, 128, 0, stream>>>(att, Wo, bo, Wih, bih, bhh, XW);
  k_rnn<<<NB, 64, 0, stream>>>(XW, Whh, r1w, r1b, r2w, r2b, r3w, r3b,
                               r4w, r4b, out);
}

// Round 13
// 182.978 us; speedup vs baseline: 1.3006x; 1.3006x over previous
//
#include <hip/hip_runtime.h>
#include <hip/hip_bf16.h>

// All tensors are float32 (verified R2/R3: runtime dtype probe took the f32
// branch; bf16 interpretation NaN'd in R1/R4). Output float32.
//
// k_rnn floor note (R6-R12): seven structural variants of the 64-step RNN
// tie at 42-47 us. The cost is per-step serial latency (LDS h round-trip +
// barrier + FMA/shfl/exp ~500-650 cyc) at DVFS-reduced clock (~1 GHz for a
// 16-block launch). Invariant to LDS instr count, conflicts, wave count,
// XW placement. This file is the best-measured configuration (R8/R9).

#define NB 16
#define NL 256
#define NLQ 64
#define NDIN 32
#define NET 128
#define NH 4
#define NETK 32

// Padded LDS layout for h/tmp: halves at float offsets 0 and 68 (R8:
// verified SQ_LDS_BANK_CONFLICT -> 0).
#define HPAD 136
#define PAD(i) ((i) + 4 * ((i) >> 6))

// ---------------------------------------------------------------------------
// Kernel 1: time embedding + K/Q projection, 8 rows per block.
// grid = 512 (k-rows) + 8 (q-rows) = 520 blocks, 128 threads.
// ---------------------------------------------------------------------------
__global__ __launch_bounds__(128) void k_embed_proj(
    const float* __restrict__ ts, const float* __restrict__ query,
    const float* __restrict__ w_lin, const float* __restrict__ b_lin,
    const float* __restrict__ w_per, const float* __restrict__ b_per,
    const float* __restrict__ Wk, const float* __restrict__ bk,
    const float* __restrict__ Wq, const float* __restrict__ bq,
    float* __restrict__ kproj, float* __restrict__ qproj) {
  __shared__ float emb[8 * NET];
  int g = blockIdx.x;
  int j = threadIdx.x;
  bool isQ = (g >= 512);
  int base = (isQ ? g - 512 : g) * 8;
  float wl_ = w_lin[0], bl_ = b_lin[0];
  float wp = (j > 0) ? w_per[j - 1] : 0.f;
  float bp = (j > 0) ? b_per[j - 1] : 0.f;
#pragma unroll
  for (int rr = 0; rr < 8; rr++) {
    float t = isQ ? query[base + rr] : ts[base + rr];
    emb[rr * NET + j] = (j == 0) ? (t * wl_ + bl_) : sinf(t * wp + bp);
  }
  __syncthreads();
  const float* W = isQ ? Wq : Wk;
  float bias = isQ ? bq[j] : bk[j];
  float acc[8];
#pragma unroll
  for (int rr = 0; rr < 8; rr++) acc[rr] = bias;
#pragma unroll 4
  for (int i = 0; i < NET; i++) {
    float wv = W[i * NET + j];
#pragma unroll
    for (int rr = 0; rr < 8; rr++) acc[rr] += emb[rr * NET + i] * wv;
  }
  float* dst = isQ ? qproj : kproj;
#pragma unroll
  for (int rr = 0; rr < 8; rr++) dst[(size_t)(base + rr) * NET + j] = acc[rr];
}

// ---------------------------------------------------------------------------
// Kernel 2: attention. block = (b, h, qgroup of 4). grid = 16*4*16 = 1024
// blocks, 256 threads. LDS ~38 KB.
// Masked softmax collapses per-channel: att_x = sum(e*m*x)/sum(e*m);
// all-masked channel => uniform softmax => mean(x), att_m = 0.
// ---------------------------------------------------------------------------
__global__ __launch_bounds__(256) void k_attn(
    const float* __restrict__ x, const float* __restrict__ mask,
    const float* __restrict__ qproj, const float* __restrict__ kproj,
    float* __restrict__ att) {
  const float SC = 0.17677669529663687f;  // 1/sqrt(32)
  int blk = blockIdx.x;
  int qg = blk & 15;
  int h  = (blk >> 4) & 3;
  int b  = blk >> 6;
  int t  = threadIdx.x;

  __shared__ float xs[NL * NDIN];  // 32 KB
  __shared__ unsigned mb[NL];      // 1 KB
  __shared__ float es[4 * NL];     // 4 KB
  __shared__ float qs[4 * NETK];   // 512 B

  if (t < 128) {
    int qq = t >> 5, i = t & 31;
    qs[t] = qproj[(qg * 4 + qq) * NET + h * NETK + i];
  }
  {
    const float4* src = (const float4*)(x + (size_t)b * NL * NDIN);
    float4* dst = (float4*)xs;
#pragma unroll
    for (int u = 0; u < 8; u++) dst[t + 256 * u] = src[t + 256 * u];
  }
  {
    const float4* mr4 = (const float4*)(mask + (size_t)(b * NL + t) * NDIN);
    unsigned bits = 0;
#pragma unroll
    for (int u = 0; u < 8; u++) {
      float4 m = mr4[u];
      bits |= (m.x != 0.f ? 1u : 0u) << (4 * u);
      bits |= (m.y != 0.f ? 1u : 0u) << (4 * u + 1);
      bits |= (m.z != 0.f ? 1u : 0u) << (4 * u + 2);
      bits |= (m.w != 0.f ? 1u : 0u) << (4 * u + 3);
    }
    mb[t] = bits;
  }
  __syncthreads();

  // phase A: scores -> exp
  {
    float kr[NETK];
    const float4* kp =
        (const float4*)(kproj + (size_t)(b * NL + t) * NET + h * NETK);
#pragma unroll
    for (int i = 0; i < 8; i++) {
      float4 v = kp[i];
      kr[4 * i] = v.x; kr[4 * i + 1] = v.y;
      kr[4 * i + 2] = v.z; kr[4 * i + 3] = v.w;
    }
#pragma unroll
    for (int qq = 0; qq < 4; qq++) {
      const float* qv = &qs[qq * NETK];
      float s0 = 0.f, s1 = 0.f;
#pragma unroll
      for (int i = 0; i < NETK; i += 2) {
        s0 += qv[i] * kr[i];
        s1 += qv[i + 1] * kr[i + 1];
      }
      es[qq * NL + t] = __expf((s0 + s1) * SC);
    }
  }
  __syncthreads();

  // phase B: lane pair (s = t&1) -> (qq = wave index, c)
  {
    int s = t & 1;
    int p = t >> 1;       // 0..127
    int qq = p >> 5;      // == wave id: uniform per wave
    int c  = p & 31;
    int k0 = s * 128;
    float den = 0.f, num = 0.f, sumx = 0.f;
#pragma unroll 4
    for (int k = k0; k < k0 + 128; k++) {
      float e  = es[qq * NL + k];
      float mv = ((mb[k] >> c) & 1u) ? 1.f : 0.f;
      float xv = xs[k * NDIN + c];
      sumx += xv;
      e *= mv;
      den += e;
      num += e * xv;
    }
    den  += __shfl_xor(den, 1, 64);
    num  += __shfl_xor(num, 1, 64);
    sumx += __shfl_xor(sumx, 1, 64);
    if (s == 0) {
      bool any = (den > 0.f);
      float ax = any ? (num / den) : (sumx * (1.f / 256.f));
      float am = any ? 1.f : 0.f;
      int q = qg * 4 + qq;
      float* ao = att + (size_t)((b * NLQ + q) * NH + h) * 64;
      ao[c]      = ax;
      ao[32 + c] = am;
    }
  }
}

// ---------------------------------------------------------------------------
// Kernel 3: out = att @ Wo + bo; XW = out @ W_ih + b_ih + b_hh.
// grid = B*LQ = 1024 blocks, 128 threads.
// ---------------------------------------------------------------------------
__global__ __launch_bounds__(128) void k_out_xw(
    const float* __restrict__ att,
    const float* __restrict__ Wo, const float* __restrict__ bo,
    const float* __restrict__ Wih, const float* __restrict__ bih,
    const float* __restrict__ bhh, float* __restrict__ XW) {
  int r = blockIdx.x;
  int j = threadIdx.x;
  __shared__ float arow[NH * 64];
  __shared__ float orow[NET];
  arow[j]       = att[(size_t)r * 256 + j];
  arow[j + 128] = att[(size_t)r * 256 + 128 + j];
  __syncthreads();
  float a0 = bo[j], a1 = 0.f, a2 = 0.f, a3 = 0.f;
#pragma unroll 8
  for (int u = 0; u < 256; u += 4) {
    a0 += arow[u]     * Wo[(u)     * NET + j];
    a1 += arow[u + 1] * Wo[(u + 1) * NET + j];
    a2 += arow[u + 2] * Wo[(u + 2) * NET + j];
    a3 += arow[u + 3] * Wo[(u + 3) * NET + j];
  }
  orow[j] = (a0 + a1) + (a2 + a3);
  __syncthreads();
  float b0 = bih[j] + bhh[j], b1 = 0.f, b2 = 0.f, b3 = 0.f;
#pragma unroll 8
  for (int e = 0; e < NET; e += 4) {
    b0 += orow[e]     * Wih[(e)     * NET + j];
    b1 += orow[e + 1] * Wih[(e + 1) * NET + j];
    b2 += orow[e + 2] * Wih[(e + 2) * NET + j];
    b3 += orow[e + 3] * Wih[(e + 3) * NET + j];
  }
  XW[(size_t)r * NET + j] = (b0 + b1) + (b2 + b3);
}

// ---------------------------------------------------------------------------
// helper: dst[PAD(j)] = b[j] + sum_i src[i] * W[i*128+j], split-2 over s.
// src/dst use the PAD layout (halves at float offsets 0 and 68).
// ---------------------------------------------------------------------------
__device__ __forceinline__ void layer128(const float* src_lds,
                                         const float* __restrict__ W,
                                         const float* __restrict__ bvec,
                                         float* dst_lds, int j, int s) {
  const float4* h4 = (const float4*)(src_lds + s * 68);
  float a0 = 0.f, a1 = 0.f, a2 = 0.f, a3 = 0.f;
#pragma unroll
  for (int i = 0; i < 16; i++) {
    float4 hv = h4[i];
    int base = (s * 64 + 4 * i) * NET + j;
    a0 += hv.x * W[base];
    a1 += hv.y * W[base + NET];
    a2 += hv.z * W[base + 2 * NET];
    a3 += hv.w * W[base + 3 * NET];
  }
  float acc = (a0 + a1) + (a2 + a3);
  acc += __shfl_xor(acc, 1, 64);
  if (s == 0) dst_lds[PAD(j)] = acc + bvec[j];
}

// ---------------------------------------------------------------------------
// Kernel 4: sequential RNN (64 steps) + regressor. grid = 16, 256 threads.
// thread = (j = tid>>1, s = tid&1). Whh half-column (64 f32, promotes to
// regs — R3/R6/R8/R9 evidence). XW staged to LDS once, read per step (the
// read is issued at the top of the step, independent of h). h double-
// buffered in PADDED LDS (conflicts = 0). One barrier per step.
// Measured floor: ~42 us (see header note).
// ---------------------------------------------------------------------------
__global__ __launch_bounds__(256, 1) void k_rnn(
    const float* __restrict__ XW, const float* __restrict__ Whh,
    const float* __restrict__ r1w, const float* __restrict__ r1b,
    const float* __restrict__ r2w, const float* __restrict__ r2b,
    const float* __restrict__ r3w, const float* __restrict__ r3b,
    const float* __restrict__ r4w, const float* __restrict__ r4b,
    float* __restrict__ out) {
  int b = blockIdx.x;
  int tid = threadIdx.x;
  int s = tid & 1;
  int j = tid >> 1;
  __shared__ float xwl[NLQ * NET];  // 32 KB, staged once
  __shared__ float hb[2][HPAD];
  __shared__ float tmp[HPAD];

  // stage XW slice for this batch (coalesced float4)
  {
    const float4* src = (const float4*)(XW + (size_t)b * NLQ * NET);
    float4* dst = (float4*)xwl;
#pragma unroll
    for (int u = 0; u < 8; u++) dst[tid + 256 * u] = src[tid + 256 * u];
  }
  // Whh half-column in registers (constant indices after full unroll)
  float w[64];
#pragma unroll
  for (int i = 0; i < 64; i++) w[i] = Whh[(s * 64 + i) * NET + j];

  if (tid < 128) hb[0][PAD(tid)] = 0.f;
  __syncthreads();

  for (int t = 0; t < NLQ; t++) {
    // issue the XW read first: independent of h, latency hides under FMAs
    float xwv = xwl[t * NET + j];
    const float4* h4 = (const float4*)&hb[t & 1][s * 68];
    float a0 = 0.f, a1 = 0.f, a2 = 0.f, a3 = 0.f;
#pragma unroll
    for (int i = 0; i < 16; i++) {
      float4 hv = h4[i];
      a0 += hv.x * w[4 * i];
      a1 += hv.y * w[4 * i + 1];
      a2 += hv.z * w[4 * i + 2];
      a3 += hv.w * w[4 * i + 3];
    }
    float acc = (a0 + a1) + (a2 + a3);
    acc += __shfl_xor(acc, 1, 64);
    if (s == 0) {
      float z = acc + xwv;
      float e2 = __expf(2.f * z);
      hb[(t + 1) & 1][PAD(j)] = 1.f - 2.f / (e2 + 1.f);  // tanh(z)
    }
    __syncthreads();
  }
  // final h is in hb[0]

  layer128(hb[0], r1w, r1b, tmp, j, s);
  __syncthreads();
  layer128(tmp, r2w, r2b, hb[1], j, s);
  __syncthreads();
  layer128(hb[1], r3w, r3b, hb[0], j, s);
  __syncthreads();
  if (tid < 64) {
    int jj = tid >> 3, p = tid & 7;
    float y = 0.f;
#pragma unroll
    for (int i = 0; i < 16; i++) {
      int ii = p * 16 + i;
      y += hb[0][PAD(ii)] * r4w[ii * 8 + jj];
    }
    y += __shfl_xor(y, 1, 64);
    y += __shfl_xor(y, 2, 64);
    y += __shfl_xor(y, 4, 64);
    if (p == 0) out[b * 8 + jj] = y + r4b[jj];
  }
}

// ---------------------------------------------------------------------------
extern "C" void kernel_launch(void* const* d_in, const int* in_sizes, int n_in,
                              void* d_out, int out_size, void* d_ws, size_t ws_size,
                              hipStream_t stream) {
  const float* x     = (const float*)d_in[0];
  const float* ts    = (const float*)d_in[1];
  const float* mask  = (const float*)d_in[2];
  const float* query = (const float*)d_in[3];
  const float* w_lin = (const float*)d_in[4];
  const float* b_lin = (const float*)d_in[5];
  const float* w_per = (const float*)d_in[6];
  const float* b_per = (const float*)d_in[7];
  const float* Wq    = (const float*)d_in[8];
  const float* bq    = (const float*)d_in[9];
  const float* Wk    = (const float*)d_in[10];
  const float* bk    = (const float*)d_in[11];
  const float* Wo    = (const float*)d_in[12];
  const float* bo    = (const float*)d_in[13];
  const float* Wih   = (const float*)d_in[14];
  const float* bih   = (const float*)d_in[15];
  const float* Whh   = (const float*)d_in[16];
  const float* bhh   = (const float*)d_in[17];
  const float* r1w   = (const float*)d_in[18];
  const float* r1b   = (const float*)d_in[19];
  const float* r2w   = (const float*)d_in[20];
  const float* r2b   = (const float*)d_in[21];
  const float* r3w   = (const float*)d_in[22];
  const float* r3b   = (const float*)d_in[23];
  const float* r4w   = (const float*)d_in[24];
  const float* r4b   = (const float*)d_in[25];
  float* out = (float*)d_out;

  float* ws    = (float*)d_ws;
  float* kproj = ws;                  // 4096*128 = 524288
  float* qproj = ws + 524288;         // 64*128   = 8192
  float* att   = ws + 532480;         // 1024*256 = 262144
  float* XW    = ws + 794624;         // 1024*128 = 131072

  k_embed_proj<<<520, 128, 0, stream>>>(
      ts, query, w_lin, b_lin, w_per, b_per, Wk, bk, Wq, bq, kproj, qproj);
  k_attn<<<NB * NH * 16, 256, 0, stream>>>(x, mask, qproj, kproj, att);
  k_out_xw<<<NB * NLQ, 128, 0, stream>>>(att, Wo, bo, Wih, bih, bhh, XW);
  k_rnn<<<NB, 256, 0, stream>>>(XW, Whh, r1w, r1b, r2w, r2b, r3w, r3b,
                                r4w, r4b, out);
}